// Round 9
// baseline (218.261 us; speedup 1.0000x reference)
//
#include <hip/hip_runtime.h>
#include <cstdint>
#include <cstddef>

// DigitCapsule dynamic routing, fp32.
// x[256,1152,8], W[1152,10,16,8], out v[256,10,16].
// Design: lane = q*16 + d. d-reductions (logits, squash) are 16-lane
// xor-butterflies via ds_swizzle -> no barriers in capsV.
// vsum trick: logits at round r = votes . (v0+...+v_{r-1}).
// R9 = R6 geometry (CA=12, 2-b/thread, waves_per_eu(3,4) -> proven VGPR 84)
// with the arithmetic re-expressed as PACKED fp32 (v_pk_fma_f32 etc. via
// <2 x float> ext_vector): dots accumulate in even/odd p-pairs, softmax
// packs the two b's per float2. ~40% fewer VALU issue slots; loads and
// loop structure untouched (R6's counters: VALU issue = 20.2us of 43.9us,
// so op count is the binding alongside stalls).
constexpr int Bn = 256, In = 1152, Pn = 8, Jn = 10, Dn = 16;
constexpr int CA = 12, NCH = In / CA;  // 96 chunks

typedef float v2f __attribute__((ext_vector_type(2)));

template <int MASK>
__device__ __forceinline__ float swzadd(float v) {
  const int s = __builtin_amdgcn_ds_swizzle(__float_as_int(v), MASK);
  return v + __int_as_float(s);
}

template <int MASK>
__device__ __forceinline__ v2f swzadd2(v2f v) {
  const int sx = __builtin_amdgcn_ds_swizzle(__float_as_int(v.x), MASK);
  const int sy = __builtin_amdgcn_ds_swizzle(__float_as_int(v.y), MASK);
  v2f s;
  s.x = __int_as_float(sx);
  s.y = __int_as_float(sy);
  return v + s;  // v_pk_add_f32
}

// Sum over the 16 lanes of each row (lane&15 = d); every lane gets the sum.
// ds_swizzle BitMode: offset = xor<<10 | or<<5 | and(0x1F). LDS pipe.
__device__ __forceinline__ float rowsum16(float v) {
  v = swzadd<0x041F>(v);
  v = swzadd<0x081F>(v);
  v = swzadd<0x101F>(v);
  v = swzadd<0x201F>(v);
  return v;
}

__device__ __forceinline__ v2f rowsum16v(v2f v) {
  v = swzadd2<0x041F>(v);  // xor 1
  v = swzadd2<0x081F>(v);  // xor 2
  v = swzadd2<0x101F>(v);  // xor 4
  v = swzadd2<0x201F>(v);  // xor 8
  return v;
}

// Packed dot over p: returns {sum of even p terms, sum of odd p terms}.
// 1 pk_mul + 3 pk_fma; caller adds the two halves.
__device__ __forceinline__ v2f pkdot8(const float4 w0, const float4 w1,
                                      const float4 x0, const float4 x1) {
  v2f wa, wb, wc, wd, xa, xb, xc, xd;
  wa.x = w0.x; wa.y = w0.y; wb.x = w0.z; wb.y = w0.w;
  wc.x = w1.x; wc.y = w1.y; wd.x = w1.z; wd.y = w1.w;
  xa.x = x0.x; xa.y = x0.y; xb.x = x0.z; xb.y = x0.w;
  xc.x = x1.x; xc.y = x1.y; xd.x = x1.z; xd.y = x1.w;
  v2f acc = wa * xa;
  acc = __builtin_elementwise_fma(wb, xb, acc);
  acc = __builtin_elementwise_fma(wc, xc, acc);
  acc = __builtin_elementwise_fma(wd, xd, acc);
  return acc;
}

// capsV: one routing round's weighted vote sum over an i-chunk, 2 b's/thread.
// thread: d = t&15, q = t>>4; b0 = blockIdx.y*32 + q, b1 = b0 + 16.
// block = (chunk, b-group of 32). Per (i,j): one 32B W load -> two dots.
// Softmax state packed as float2 {b0, b1}.
// MODE 0: softmax of zero logits = 0.1 exactly -> raw vote sum * 0.1.
template <int MODE>
__global__ __launch_bounds__(256)
__attribute__((amdgpu_waves_per_eu(3, 4)))
void capsV(const float* __restrict__ x, const float* __restrict__ w,
           const float* __restrict__ vsumT, float* __restrict__ spart) {
  const int t = threadIdx.x;
  const int d = t & 15, q = t >> 4;
  const int ch = blockIdx.x;
  const int b0 = blockIdx.y * 32 + q, b1 = b0 + 16;

  v2f vs2[Jn], acc2[Jn];
  #pragma unroll
  for (int j = 0; j < Jn; ++j) {
    acc2[j] = (v2f)(0.f);
    if (MODE) {
      vs2[j].x = vsumT[((size_t)j * Bn + b0) * Dn + d];
      vs2[j].y = vsumT[((size_t)j * Bn + b1) * Dn + d];
    }
  }

  const int i0 = ch * CA;
  const float* xp0 = x + ((size_t)b0 * In + i0) * Pn;
  const float* xp1 = x + ((size_t)b1 * In + i0) * Pn;
  const float* wp = w + (((size_t)i0 * Jn) * Dn + d) * Pn;

  for (int ii = 0; ii < CA; ++ii) {
    const float4 xa0 = reinterpret_cast<const float4*>(xp0)[0];
    const float4 xa1 = reinterpret_cast<const float4*>(xp0)[1];
    const float4 xb0 = reinterpret_cast<const float4*>(xp1)[0];
    const float4 xb1 = reinterpret_cast<const float4*>(xp1)[1];

    v2f vt2[Jn];
    #pragma unroll
    for (int j = 0; j < Jn; ++j) {
      const float4* wj =
          reinterpret_cast<const float4*>(wp + (size_t)j * (Dn * Pn));
      const float4 w0 = wj[0], w1 = wj[1];
      const v2f pa = pkdot8(w0, w1, xa0, xa1);  // b0, even/odd halves
      const v2f pb = pkdot8(w0, w1, xb0, xb1);  // b1
      vt2[j].x = pa.x + pa.y;
      vt2[j].y = pb.x + pb.y;
    }

    if (MODE) {
      v2f l2[Jn];
      #pragma unroll
      for (int j = 0; j < Jn; ++j) l2[j] = rowsum16v(vt2[j] * vs2[j]);
      // softmax over j; logits are O(0.1) so no max-subtraction needed.
      v2f ssum = (v2f)(0.f);
      #pragma unroll
      for (int j = 0; j < Jn; ++j) {
        l2[j].x = __expf(l2[j].x);
        l2[j].y = __expf(l2[j].y);
        ssum += l2[j];
      }
      v2f inv2;
      inv2.x = __builtin_amdgcn_rcpf(ssum.x);
      inv2.y = __builtin_amdgcn_rcpf(ssum.y);
      #pragma unroll
      for (int j = 0; j < Jn; ++j)
        acc2[j] = __builtin_elementwise_fma(l2[j] * inv2, vt2[j], acc2[j]);
    } else {
      #pragma unroll
      for (int j = 0; j < Jn; ++j) acc2[j] += vt2[j];  // v_pk_add_f32
    }

    xp0 += Pn;
    xp1 += Pn;
    wp += (size_t)Jn * Dn * Pn;
  }

  const float cs = MODE ? 1.f : 0.1f;
  #pragma unroll
  for (int j = 0; j < Jn; ++j) {
    spart[(((size_t)ch * Jn + j) * Bn + b0) * Dn + d] = acc2[j].x * cs;
    spart[(((size_t)ch * Jn + j) * Bn + b1) * Dn + d] = acc2[j].y * cs;
  }
}

// capsF: reduce 96 chunk-partials, squash. 1024 threads: 4 chunk-groups
// (cg = t>>8) each privately sum 24 chunks; LDS combine across cg; squash
// norm via rowsum16 in the t<256 tail. block = (j, b-group of 16).
// MODE 0: vsumT = v ; MODE 1: vsumT += v ; MODE 2: out[b][j][d] = v.
template <int MODE>
__global__ __launch_bounds__(1024) void capsF(
    const float* __restrict__ spart, float* __restrict__ vsumT,
    float* __restrict__ out) {
  __shared__ float red[4][16][16];
  const int t = threadIdx.x;
  const int cg = t >> 8, r = t & 255, g = r >> 4, d = r & 15;
  const int j = blockIdx.x, b = blockIdx.y * 16 + g;

  const size_t cstride = (size_t)Jn * Bn * Dn;  // one chunk, in floats
  const size_t cstep = 4 * cstride;             // stride between my chunks
  const float* sp = spart + (((size_t)cg * Jn + j) * Bn + b) * Dn + d;
  float s0 = 0.f, s1 = 0.f;
  #pragma unroll 4
  for (int k = 0; k < NCH / 4; k += 2) {
    s0 += sp[0];
    s1 += sp[cstep];
    sp += 2 * cstep;
  }
  red[cg][g][d] = s0 + s1;
  __syncthreads();
  if (t < 256) {
    const float z = red[0][g][d] + red[1][g][d] + red[2][g][d] + red[3][g][d];
    const float n2 = rowsum16(z * z);
    const float sc = n2 / (1.f + n2) / sqrtf(n2 + 1e-7f);
    const float v = z * sc;
    if (MODE == 2) {
      out[((size_t)b * Jn + j) * Dn + d] = v;
    } else if (MODE == 1) {
      vsumT[((size_t)j * Bn + b) * Dn + d] += v;
    } else {
      vsumT[((size_t)j * Bn + b) * Dn + d] = v;
    }
  }
}

extern "C" void kernel_launch(void* const* d_in, const int* in_sizes, int n_in,
                              void* d_out, int out_size, void* d_ws, size_t ws_size,
                              hipStream_t stream) {
  const float* x = (const float*)d_in[0];  // [256,1152,8]
  const float* w = (const float*)d_in[1];  // [1152,10,16,8]
  float* vsumT = (float*)d_ws;                      // [J][B][D]   0.16 MB
  float* spart = vsumT + (size_t)Jn * Bn * Dn;      // [NCH][J][B][D] 15.7 MB
  float* out = (float*)d_out;                       // [256,10,16]

  const dim3 gV(NCH, Bn / 32), gF(Jn, Bn / 16);

  capsV<0><<<gV, 256, 0, stream>>>(x, w, nullptr, spart);
  capsF<0><<<gF, 1024, 0, stream>>>(spart, vsumT, out);   // vsum = v0

  capsV<1><<<gV, 256, 0, stream>>>(x, w, vsumT, spart);   // round 1
  capsF<1><<<gF, 1024, 0, stream>>>(spart, vsumT, out);   // vsum += v1

  capsV<1><<<gV, 256, 0, stream>>>(x, w, vsumT, spart);   // round 2
  capsF<2><<<gF, 1024, 0, stream>>>(spart, vsumT, out);   // out = v2
}